// Round 16
// baseline (124.206 us; speedup 1.0000x reference)
//
#include <hip/hip_runtime.h>
#include <stdint.h>

using bf16x8  = __attribute__((ext_vector_type(8))) short;           // 8 bf16 = 4 VGPR
using f32x4   = __attribute__((ext_vector_type(4))) float;
using f32x16  = __attribute__((ext_vector_type(16))) float;
using ushort8 = __attribute__((ext_vector_type(8))) unsigned short;  // 16B
using ushort4v= __attribute__((ext_vector_type(4))) unsigned short;
using uint2v  = __attribute__((ext_vector_type(2))) unsigned int;
using f32x4v  = __attribute__((ext_vector_type(4))) float;

typedef __attribute__((address_space(1))) const unsigned int* gas_ptr;
typedef __attribute__((address_space(3))) unsigned int*       las_ptr;

__device__ __forceinline__ void gload_lds16(const unsigned short* g, unsigned short* l) {
    // async global->LDS, 16B/lane; LDS dest = wave-uniform base + lane*16
    __builtin_amdgcn_global_load_lds((gas_ptr)(const void*)g, (las_ptr)(void*)l, 16, 0, 0);
}

__device__ __forceinline__ unsigned short f2bf(float f) {
    union { float f; uint32_t u; } x; x.f = f;
    uint32_t u = x.u;
    uint32_t r = u + 0x7fffu + ((u >> 16) & 1u);   // RNE
    return (unsigned short)(r >> 16);
}
__device__ __forceinline__ float bf2f(unsigned short u) {
    union { uint32_t u; float f; } x; x.u = ((uint32_t)u) << 16;
    return x.f;
}

__device__ __forceinline__ f32x4 mfma16(bf16x8 a, bf16x8 b, f32x4 c) {
    return __builtin_amdgcn_mfma_f32_16x16x32_bf16(a, b, c, 0, 0, 0);
}
__device__ __forceinline__ f32x16 mfma32(bf16x8 a, bf16x8 b, f32x16 c) {
    return __builtin_amdgcn_mfma_f32_32x32x16_bf16(a, b, c, 0, 0, 0);
}

__device__ __forceinline__ unsigned int cvtpk_bf16(float lo, float hi) {
    unsigned int r;
    asm("v_cvt_pk_bf16_f32 %0, %1, %2" : "=v"(r) : "v"(lo), "v"(hi));
    return r;
}
__device__ __forceinline__ void plswap(unsigned int& a, unsigned int& b) {
    asm("v_permlane32_swap_b32 %0, %1" : "+v"(a), "+v"(b));
}
__device__ __forceinline__ float m3(float a, float b, float c) {   // fuses to v_max3_f32
    return fmaxf(fmaxf(a, b), c);
}

// ---------------- fused prep: cast x + pack w_qkv^T + pack w_o^T ----------------
// blocks [0,4096): cast x->bf16; [4096,4864): wqkv transpose; [4864,5120): wo transpose.

__global__ void prep_kernel(const float* __restrict__ x,
                            const float* __restrict__ wq, const float* __restrict__ wk,
                            const float* __restrict__ wv, const float* __restrict__ wo,
                            unsigned short* __restrict__ xb, unsigned short* __restrict__ wpT,
                            unsigned short* __restrict__ woT)
{
    __shared__ float tile[64][65];
    const int bid = blockIdx.x;
    const int tid = threadIdx.x;

    if (bid < 4096) {
        int i = bid * 256 + tid;
        f32x4v v = ((const f32x4v*)x)[i];
        ushort4v o;
        o[0] = f2bf(v[0]); o[1] = f2bf(v[1]); o[2] = f2bf(v[2]); o[3] = f2bf(v[3]);
        ((ushort4v*)xb)[i] = o;
    } else if (bid < 4864) {
        const int b2 = bid - 4096;
        const int mm = b2 >> 4;                 // 0..47
        const int s = mm >> 4, hh = mm & 15;
        const float* src = ((s == 0) ? wq : (s == 1) ? wk : wv) + (size_t)hh * 1024 * 64;
        const int k0 = (b2 & 15) * 64;
        const int c = tid & 63, rg = tid >> 6;
#pragma unroll
        for (int i = 0; i < 16; ++i) {
            int r = rg * 16 + i;
            tile[r][c] = src[(size_t)(k0 + r) * 64 + c];
        }
        __syncthreads();
        unsigned short* dst = wpT + ((size_t)s * 1024 + hh * 64) * 1024 + k0;
        const int kc = tid & 63, dg = tid >> 6;
#pragma unroll
        for (int i = 0; i < 16; ++i) {
            int d = dg * 16 + i;
            dst[(size_t)d * 1024 + kc] = f2bf(tile[kc][d]);
        }
    } else {
        const int b3 = bid - 4864;
        const int r0 = (b3 >> 4) * 64;          // k
        const int c0 = (b3 & 15) * 64;          // m
        const int c = tid & 63, rg = tid >> 6;
#pragma unroll
        for (int i = 0; i < 16; ++i) {
            int r = rg * 16 + i;
            tile[r][c] = wo[(size_t)(r0 + r) * 1024 + c0 + c];
        }
        __syncthreads();
        const int kc = tid & 63, mg = tid >> 6;
#pragma unroll
        for (int i = 0; i < 16; ++i) {
            int m = mg * 16 + i;
            woT[(size_t)(c0 + m) * 1024 + r0 + kc] = f2bf(tile[kc][m]);
        }
    }
}

// ---------------- GEMM (A row-major [M][K], BT row-major [N][K]) ----------------
// MODE 0: scatter Q/K into [bh][l][64] and V TRANSPOSED into [bh][64][2048].
// MODE 1: fp32 C row-major.

template<int MODE, int BN>
__global__ __launch_bounds__(256) void gemm_bt(
    const unsigned short* __restrict__ A,
    const unsigned short* __restrict__ BT,
    float* __restrict__ Cf,
    unsigned short* __restrict__ Q,
    unsigned short* __restrict__ Kq,
    unsigned short* __restrict__ V,
    int M, int N, int K)
{
    constexpr int NF = BN / 32;
    __shared__ unsigned short As[128 * 64];
    __shared__ unsigned short Bs[BN * 64];
    const int tid  = threadIdx.x;
    const int lane = tid & 63;
    const int wave = tid >> 6;
    const int wm = wave >> 1, wn = wave & 1;
    const int l15 = lane & 15, l4 = lane >> 4;
    const int row0 = blockIdx.y * 128;
    const int col0 = blockIdx.x * BN;

    f32x4 acc[4][NF];
#pragma unroll
    for (int i = 0; i < 4; ++i)
#pragma unroll
        for (int j = 0; j < NF; ++j) acc[i][j] = (f32x4){0.f, 0.f, 0.f, 0.f};

    for (int k0 = 0; k0 < K; k0 += 64) {
        __syncthreads();
#pragma unroll
        for (int it = 0; it < 4; ++it) {
            int cb = (it * 4 + wave) * 64;
            int c  = cb + lane;
            int r  = c >> 3, c8 = c & 7;
            int sc8 = c8 ^ (r & 7);
            gload_lds16(&A[(size_t)(row0 + r) * K + k0 + sc8 * 8], &As[cb * 8]);
        }
#pragma unroll
        for (int it = 0; it < NF; ++it) {
            int cb = (it * 4 + wave) * 64;
            int c  = cb + lane;
            int r  = c >> 3, c8 = c & 7;
            int sc8 = c8 ^ (r & 7);
            gload_lds16(&BT[(size_t)(col0 + r) * K + k0 + sc8 * 8], &Bs[cb * 8]);
        }
        __syncthreads();
#pragma unroll
        for (int kk = 0; kk < 2; ++kk) {
            bf16x8 af[4], bfr[NF];
#pragma unroll
            for (int m = 0; m < 4; ++m) {
                int r   = wm * 64 + m * 16 + l15;
                int blk = (kk * 4 + l4) ^ (r & 7);
                af[m] = *(const bf16x8*)&As[r * 64 + blk * 8];
            }
#pragma unroll
            for (int n = 0; n < NF; ++n) {
                int r   = wn * (BN / 2) + n * 16 + l15;
                int blk = (kk * 4 + l4) ^ (r & 7);
                bfr[n] = *(const bf16x8*)&Bs[r * 64 + blk * 8];
            }
#pragma unroll
            for (int m = 0; m < 4; ++m)
#pragma unroll
                for (int n = 0; n < NF; ++n)
                    acc[m][n] = mfma16(af[m], bfr[n], acc[m][n]);
        }
    }

#pragma unroll
    for (int m = 0; m < 4; ++m) {
        int gr0 = row0 + wm * 64 + m * 16 + l4 * 4;
#pragma unroll
        for (int n = 0; n < NF; ++n) {
            int gc = col0 + wn * (BN / 2) + n * 16 + l15;
            if (MODE == 0) {
                int s = gc >> 10, rem = gc & 1023;
                int hh = rem >> 6, dd = rem & 63;
                int bb = gr0 >> 11, ll = gr0 & 2047;
                if (s == 2) {
                    // V transposed: [bh][d][2048], 4 consecutive l -> 8B store
                    ushort4v o;
#pragma unroll
                    for (int r = 0; r < 4; ++r) o[r] = f2bf(acc[m][n][r]);
                    *(ushort4v*)&V[(((size_t)bb * 16 + hh) * 64 + dd) * 2048 + ll] = o;
                } else {
                    unsigned short* dst = (s == 0) ? Q : Kq;
#pragma unroll
                    for (int r = 0; r < 4; ++r)
                        dst[(((size_t)bb * 16 + hh) * 2048 + ll + r) * 64 + dd] = f2bf(acc[m][n][r]);
                }
            } else {
#pragma unroll
                for (int r = 0; r < 4; ++r)
                    Cf[(size_t)(gr0 + r) * N + gc] = acc[m][n][r];
            }
        }
    }
}

// ---------------- flash attention, swapped-QK 32x32, SINGLE-PASS, gload_lds staging ----------------
// r13/r14-proven kernel, byte-identical to r14.

__global__ __launch_bounds__(256, 4) void attn_kernel(
    const unsigned short* __restrict__ qb,
    const unsigned short* __restrict__ kb,
    const unsigned short* __restrict__ vtb,   // [bh][64][2048] bf16 (V transposed)
    const unsigned char* __restrict__ mask,
    unsigned short* __restrict__ ctxb)        // [b][l][h*64+d] bf16
{
    const int lg = blockIdx.x;
    int u = ((lg & 7) << 6) | (lg >> 3);       // bijective XCD swizzle (512 = 8*64)
    const int qt = u & 15, bh = u >> 4;
    const int b = bh >> 4;
    const int NT = 32;

    const int tid  = threadIdx.x;
    const int lane = tid & 63, wave = tid >> 6;
    const int l31  = lane & 31, hi = lane >> 5;

    __shared__ unsigned short smem[16384];  // K dbuf [0,8K); Vt dbuf [8K,16K) ushorts = 32 KB exactly

    const size_t hoff = (size_t)bh * 131072;
    const unsigned short* qh  = qb  + hoff;
    const unsigned short* kh  = kb  + hoff;
    const unsigned short* vth = vtb + hoff;
    const unsigned char*  mb  = mask + (size_t)b * 2048;

    unsigned long long mball;
    {
        const uint2v* mp = (const uint2v*)mb;
        uint2v a0 = mp[lane * 4 + 0], a1 = mp[lane * 4 + 1];
        uint2v a2 = mp[lane * 4 + 2], a3 = mp[lane * 4 + 3];
        unsigned int any = a0[0] | a0[1] | a1[0] | a1[1] | a2[0] | a2[1] | a3[0] | a3[1];
        mball = __ballot(any != 0u);
    }

    const int qrow = qt * 128 + wave * 32 + l31;
    bf16x8 qf[4];
#pragma unroll
    for (int ki = 0; ki < 4; ++ki)
        qf[ki] = *(const bf16x8*)&qh[(size_t)qrow * 64 + ki * 16 + hi * 8];

    const f32x16 zf = {0,0,0,0,0,0,0,0,0,0,0,0,0,0,0,0};
    bf16x8 ones;
#pragma unroll
    for (int j = 0; j < 8; ++j) ones[j] = (short)0x3F80;

    f32x16 accA = {0,0,0,0,0,0,0,0,0,0,0,0,0,0,0,0};
    f32x16 accB = {0,0,0,0,0,0,0,0,0,0,0,0,0,0,0,0};
    f32x16 accL = {0,0,0,0,0,0,0,0,0,0,0,0,0,0,0,0};  // only [0] is consumed
    float m_r = -1e30f;
    const float SC  = 0.18033688011112042f;            // 0.125 * log2(e)
    const float THR = 44.3614195558365f;               // 8 / SC  (defer-max)

#define STAGE(KB, VB, KV0) do {                                                          \
        _Pragma("unroll")                                                                \
        for (int it_ = 0; it_ < 2; ++it_) {                                              \
            int c_ = it_ * 256 + tid;                                                    \
            int r_ = c_ >> 3, c8_ = c_ & 7;                                              \
            int sc8_ = c8_ ^ (r_ & 7);                                                   \
            gload_lds16(&kh[(size_t)((KV0) + r_) * 64 + sc8_ * 8],                       \
                        &(KB)[(it_ * 256 + wave * 64) * 8]);                             \
            gload_lds16(&vth[(size_t)r_ * 2048 + (KV0) + sc8_ * 8],                      \
                        &(VB)[(it_ * 256 + wave * 64) * 8]);                             \
        }                                                                                \
    } while (0)

    STAGE(smem, smem + 8192, 0);               // prologue -> buffer parity 0

    for (int t = 0; t < NT; ++t) {
        const int kv0 = t * 64;
        unsigned short* Kb = smem + (t & 1) * 4096;
        unsigned short* Vb = smem + 8192 + (t & 1) * 4096;
        __syncthreads();                       // drains vmcnt -> tile t staged; prev readers done
        if (t + 1 < NT) {
            unsigned short* Kn = smem + ((t + 1) & 1) * 4096;
            unsigned short* Vn = smem + 8192 + ((t + 1) & 1) * 4096;
            STAGE(Kn, Vn, kv0 + 64);           // prefetch next tile under compute
        }

        // ---- S^T = K @ Q^T ----
        f32x16 s0, s1;
        __builtin_amdgcn_s_setprio(1);
        {
            int c0 = (hi ^ (l31 & 7)) * 8;
            bf16x8 a0 = *(const bf16x8*)&Kb[l31 * 64 + c0];
            bf16x8 a1 = *(const bf16x8*)&Kb[(32 + l31) * 64 + c0];
            s0 = mfma32(a0, qf[0], zf);
            s1 = mfma32(a1, qf[0], zf);
        }
#pragma unroll
        for (int ki = 1; ki < 4; ++ki) {
            int c0 = ((ki * 2 + hi) ^ (l31 & 7)) * 8;
            bf16x8 a0 = *(const bf16x8*)&Kb[l31 * 64 + c0];
            bf16x8 a1 = *(const bf16x8*)&Kb[(32 + l31) * 64 + c0];
            s0 = mfma32(a0, qf[ki], s0);
            s1 = mfma32(a1, qf[ki], s1);
        }
        __builtin_amdgcn_s_setprio(0);

        if ((mball >> ((t & 31) * 2)) & 3ull) {            // wave-uniform mask slow path
#pragma unroll
            for (int r = 0; r < 16; ++r) {
                int keyl = (r & 3) + 8 * (r >> 2) + 4 * hi;
                if (mb[kv0 + keyl])      s0[r] = -1e30f;
                if (mb[kv0 + 32 + keyl]) s1[r] = -1e30f;
            }
        }

        // ---- online softmax (max3 tree) ----
        float mx;
        {
            float a0 = m3(s0[0],  s0[1],  s0[2]);
            float a1 = m3(s0[3],  s0[4],  s0[5]);
            float a2 = m3(s0[6],  s0[7],  s0[8]);
            float a3 = m3(s0[9],  s0[10], s0[11]);
            float a4 = m3(s0[12], s0[13], s0[14]);
            float b0 = m3(s1[0],  s1[1],  s1[2]);
            float b1 = m3(s1[3],  s1[4],  s1[5]);
            float b2 = m3(s1[6],  s1[7],  s1[8]);
            float b3 = m3(s1[9],  s1[10], s1[11]);
            float b4 = m3(s1[12], s1[13], s1[14]);
            float c0 = m3(a0, a1, s0[15]);
            float c1 = m3(a2, a3, a4);
            float c2 = m3(b0, b1, s1[15]);
            float c3 = m3(b2, b3, b4);
            mx = fmaxf(m3(c0, c1, c2), c3);
        }
        mx = fmaxf(mx, __shfl_xor(mx, 32));
        if (__any(mx > m_r + THR)) {           // defer-max (T13)
            float mn  = fmaxf(m_r, mx);
            float scl = __builtin_amdgcn_exp2f((m_r - mn) * SC);
            m_r = mn;
            accL[0] *= scl;
#pragma unroll
            for (int i = 0; i < 16; ++i) { accA[i] *= scl; accB[i] *= scl; }
        }
        const float nmc = -m_r * SC;
#pragma unroll
        for (int i = 0; i < 16; ++i) {
            s0[i] = __builtin_amdgcn_exp2f(__builtin_fmaf(s0[i], SC, nmc));
            s1[i] = __builtin_amdgcn_exp2f(__builtin_fmaf(s1[i], SC, nmc));
        }

        // ---- P -> bf16 B-fragments (T12) ----
        bf16x8 pf[4];
        {
            union { unsigned int u[4]; bf16x8 v; } f;
            unsigned int w0 = cvtpk_bf16(s0[0],  s0[1]),  w1 = cvtpk_bf16(s0[2],  s0[3]);
            unsigned int w2 = cvtpk_bf16(s0[4],  s0[5]),  w3 = cvtpk_bf16(s0[6],  s0[7]);
            unsigned int w4 = cvtpk_bf16(s0[8],  s0[9]),  w5 = cvtpk_bf16(s0[10], s0[11]);
            unsigned int w6 = cvtpk_bf16(s0[12], s0[13]), w7 = cvtpk_bf16(s0[14], s0[15]);
            plswap(w0, w2); plswap(w1, w3); plswap(w4, w6); plswap(w5, w7);
            f.u[0] = w0; f.u[1] = w1; f.u[2] = w2; f.u[3] = w3; pf[0] = f.v;
            f.u[0] = w4; f.u[1] = w5; f.u[2] = w6; f.u[3] = w7; pf[1] = f.v;
            unsigned int x0 = cvtpk_bf16(s1[0],  s1[1]),  x1 = cvtpk_bf16(s1[2],  s1[3]);
            unsigned int x2 = cvtpk_bf16(s1[4],  s1[5]),  x3 = cvtpk_bf16(s1[6],  s1[7]);
            unsigned int x4 = cvtpk_bf16(s1[8],  s1[9]),  x5 = cvtpk_bf16(s1[10], s1[11]);
            unsigned int x6 = cvtpk_bf16(s1[12], s1[13]), x7 = cvtpk_bf16(s1[14], s1[15]);
            plswap(x0, x2); plswap(x1, x3); plswap(x4, x6); plswap(x5, x7);
            f.u[0] = x0; f.u[1] = x1; f.u[2] = x2; f.u[3] = x3; pf[2] = f.v;
            f.u[0] = x4; f.u[1] = x5; f.u[2] = x6; f.u[3] = x7; pf[3] = f.v;
        }

        // ---- ctx^T += V^T @ P^T ;  l += ones @ P^T ----
        __builtin_amdgcn_s_setprio(1);
#pragma unroll
        for (int ks = 0; ks < 4; ++ks) {
            int c0 = ((ks * 2 + hi) ^ (l31 & 7)) * 8;
            bf16x8 vA = *(const bf16x8*)&Vb[l31 * 64 + c0];
            bf16x8 vB = *(const bf16x8*)&Vb[(32 + l31) * 64 + c0];
            accA = mfma32(vA, pf[ks], accA);
            accB = mfma32(vB, pf[ks], accB);
            accL = mfma32(ones, pf[ks], accL);
        }
        __builtin_amdgcn_s_setprio(0);
    }
#undef STAGE

    // ---- epilogue: normalize, LDS transpose, coalesced bf16 store ----
    __syncthreads();
    const float inv = 1.0f / accL[0];          // accL[0] = sum_k P[k][q=l31]
    const int qloc = wave * 32 + l31;
#pragma unroll
    for (int r = 0; r < 16; ++r) {
        int dA = (r & 3) + 8 * (r >> 2) + 4 * hi;
        smem[qloc * 64 + (dA ^ ((qloc & 7) * 8))]        = f2bf(accA[r] * inv);
        smem[qloc * 64 + ((32 + dA) ^ ((qloc & 7) * 8))] = f2bf(accB[r] * inv);
    }
    __syncthreads();
    const int h = bh & 15;
#pragma unroll
    for (int it = 0; it < 4; ++it) {
        int idx = tid + it * 256;
        int q = idx >> 3, c = idx & 7;
        ushort8 vv = *(const ushort8*)&smem[q * 64 + ((c * 8) ^ ((q & 7) * 8))];
        *(ushort8*)&ctxb[((size_t)(b * 2048 + qt * 128 + q)) * 1024 + h * 64 + c * 8] = vv;
    }
}

// ---------------- launch ----------------

extern "C" void kernel_launch(void* const* d_in, const int* in_sizes, int n_in,
                              void* d_out, int out_size, void* d_ws, size_t ws_size,
                              hipStream_t stream)
{
    const float* x  = (const float*)d_in[0];
    const float* wq = (const float*)d_in[1];
    const float* wk = (const float*)d_in[2];
    const float* wv = (const float*)d_in[3];
    const float* wo = (const float*)d_in[4];
    const unsigned char* mask = (const unsigned char*)d_in[5];
    float* out = (float*)d_out;

    char* ws = (char*)d_ws;
    unsigned short* xb   = (unsigned short*)(ws);                 //  8 MB  [4096][1024]
    unsigned short* wpT  = (unsigned short*)(ws + 8388608);       //  6 MB  [3072][1024]
    unsigned short* woT  = (unsigned short*)(ws + 14680064);      //  2 MB  [1024][1024]
    unsigned short* qb   = (unsigned short*)(ws + 16777216);      //  8 MB  [32][2048][64]
    unsigned short* kb   = (unsigned short*)(ws + 25165824);      //  8 MB  [32][2048][64]
    unsigned short* vtb  = (unsigned short*)(ws + 33554432);      //  8 MB  [32][64][2048] (V^T, written by gemm<0>)
    unsigned short* ctxb = (unsigned short*)(ws + 41943040);      //  8 MB  [4096][1024]

    prep_kernel<<<5120, 256, 0, stream>>>(x, wq, wk, wv, wo, xb, wpT, woT);

    gemm_bt<0,128><<<dim3(24, 32), 256, 0, stream>>>(xb, wpT, nullptr, qb, kb, vtb, 4096, 3072, 1024);

    attn_kernel<<<512, 256, 0, stream>>>(qb, kb, vtb, mask, ctxb);

    gemm_bt<1,128><<<dim3(8, 32), 256, 0, stream>>>(ctxb, woT, out, nullptr, nullptr, nullptr, 4096, 1024, 1024);
}

// Round 17
// 118.570 us; speedup vs baseline: 1.0475x; 1.0475x over previous
//
#include <hip/hip_runtime.h>
#include <stdint.h>

using bf16x8  = __attribute__((ext_vector_type(8))) short;           // 8 bf16 = 4 VGPR
using f32x4   = __attribute__((ext_vector_type(4))) float;
using f32x16  = __attribute__((ext_vector_type(16))) float;
using ushort8 = __attribute__((ext_vector_type(8))) unsigned short;  // 16B
using ushort4v= __attribute__((ext_vector_type(4))) unsigned short;
using uint2v  = __attribute__((ext_vector_type(2))) unsigned int;
using f32x4v  = __attribute__((ext_vector_type(4))) float;

typedef __attribute__((address_space(1))) const unsigned int* gas_ptr;
typedef __attribute__((address_space(3))) unsigned int*       las_ptr;

__device__ __forceinline__ void gload_lds16(const unsigned short* g, unsigned short* l) {
    // async global->LDS, 16B/lane; LDS dest = wave-uniform base + lane*16
    __builtin_amdgcn_global_load_lds((gas_ptr)(const void*)g, (las_ptr)(void*)l, 16, 0, 0);
}

__device__ __forceinline__ unsigned short f2bf(float f) {
    union { float f; uint32_t u; } x; x.f = f;
    uint32_t u = x.u;
    uint32_t r = u + 0x7fffu + ((u >> 16) & 1u);   // RNE
    return (unsigned short)(r >> 16);
}
__device__ __forceinline__ float bf2f(unsigned short u) {
    union { uint32_t u; float f; } x; x.u = ((uint32_t)u) << 16;
    return x.f;
}

__device__ __forceinline__ f32x4 mfma16(bf16x8 a, bf16x8 b, f32x4 c) {
    return __builtin_amdgcn_mfma_f32_16x16x32_bf16(a, b, c, 0, 0, 0);
}
__device__ __forceinline__ f32x16 mfma32(bf16x8 a, bf16x8 b, f32x16 c) {
    return __builtin_amdgcn_mfma_f32_32x32x16_bf16(a, b, c, 0, 0, 0);
}

__device__ __forceinline__ unsigned int cvtpk_bf16(float lo, float hi) {
    unsigned int r;
    asm("v_cvt_pk_bf16_f32 %0, %1, %2" : "=v"(r) : "v"(lo), "v"(hi));
    return r;
}
__device__ __forceinline__ void plswap(unsigned int& a, unsigned int& b) {
    asm("v_permlane32_swap_b32 %0, %1" : "+v"(a), "+v"(b));
}
__device__ __forceinline__ float m3(float a, float b, float c) {   // fuses to v_max3_f32
    return fmaxf(fmaxf(a, b), c);
}

// ---------------- fused prep: cast x + pack w_qkv^T + pack w_o^T ----------------
// blocks [0,4096): cast x->bf16; [4096,4864): wqkv transpose; [4864,5120): wo transpose.

__global__ void prep_kernel(const float* __restrict__ x,
                            const float* __restrict__ wq, const float* __restrict__ wk,
                            const float* __restrict__ wv, const float* __restrict__ wo,
                            unsigned short* __restrict__ xb, unsigned short* __restrict__ wpT,
                            unsigned short* __restrict__ woT)
{
    __shared__ float tile[64][65];
    const int bid = blockIdx.x;
    const int tid = threadIdx.x;

    if (bid < 4096) {
        int i = bid * 256 + tid;
        f32x4v v = ((const f32x4v*)x)[i];
        ushort4v o;
        o[0] = f2bf(v[0]); o[1] = f2bf(v[1]); o[2] = f2bf(v[2]); o[3] = f2bf(v[3]);
        ((ushort4v*)xb)[i] = o;
    } else if (bid < 4864) {
        const int b2 = bid - 4096;
        const int mm = b2 >> 4;                 // 0..47
        const int s = mm >> 4, hh = mm & 15;
        const float* src = ((s == 0) ? wq : (s == 1) ? wk : wv) + (size_t)hh * 1024 * 64;
        const int k0 = (b2 & 15) * 64;
        const int c = tid & 63, rg = tid >> 6;
#pragma unroll
        for (int i = 0; i < 16; ++i) {
            int r = rg * 16 + i;
            tile[r][c] = src[(size_t)(k0 + r) * 64 + c];
        }
        __syncthreads();
        unsigned short* dst = wpT + ((size_t)s * 1024 + hh * 64) * 1024 + k0;
        const int kc = tid & 63, dg = tid >> 6;
#pragma unroll
        for (int i = 0; i < 16; ++i) {
            int d = dg * 16 + i;
            dst[(size_t)d * 1024 + kc] = f2bf(tile[kc][d]);
        }
    } else {
        const int b3 = bid - 4864;
        const int r0 = (b3 >> 4) * 64;          // k
        const int c0 = (b3 & 15) * 64;          // m
        const int c = tid & 63, rg = tid >> 6;
#pragma unroll
        for (int i = 0; i < 16; ++i) {
            int r = rg * 16 + i;
            tile[r][c] = wo[(size_t)(r0 + r) * 1024 + c0 + c];
        }
        __syncthreads();
        const int kc = tid & 63, mg = tid >> 6;
#pragma unroll
        for (int i = 0; i < 16; ++i) {
            int m = mg * 16 + i;
            woT[(size_t)(c0 + m) * 1024 + r0 + kc] = f2bf(tile[kc][m]);
        }
    }
}

// ---------------- GEMM (A row-major [M][K], BT row-major [N][K]) ----------------
// MODE 0: scatter Q/K into [bh][l][64] and V TRANSPOSED into [bh][64][2048].
// MODE 1: fp32 C row-major.

template<int MODE, int BN>
__global__ __launch_bounds__(256) void gemm_bt(
    const unsigned short* __restrict__ A,
    const unsigned short* __restrict__ BT,
    float* __restrict__ Cf,
    unsigned short* __restrict__ Q,
    unsigned short* __restrict__ Kq,
    unsigned short* __restrict__ V,
    int M, int N, int K)
{
    constexpr int NF = BN / 32;
    __shared__ unsigned short As[128 * 64];
    __shared__ unsigned short Bs[BN * 64];
    const int tid  = threadIdx.x;
    const int lane = tid & 63;
    const int wave = tid >> 6;
    const int wm = wave >> 1, wn = wave & 1;
    const int l15 = lane & 15, l4 = lane >> 4;
    const int row0 = blockIdx.y * 128;
    const int col0 = blockIdx.x * BN;

    f32x4 acc[4][NF];
#pragma unroll
    for (int i = 0; i < 4; ++i)
#pragma unroll
        for (int j = 0; j < NF; ++j) acc[i][j] = (f32x4){0.f, 0.f, 0.f, 0.f};

    for (int k0 = 0; k0 < K; k0 += 64) {
        __syncthreads();
#pragma unroll
        for (int it = 0; it < 4; ++it) {
            int cb = (it * 4 + wave) * 64;
            int c  = cb + lane;
            int r  = c >> 3, c8 = c & 7;
            int sc8 = c8 ^ (r & 7);
            gload_lds16(&A[(size_t)(row0 + r) * K + k0 + sc8 * 8], &As[cb * 8]);
        }
#pragma unroll
        for (int it = 0; it < NF; ++it) {
            int cb = (it * 4 + wave) * 64;
            int c  = cb + lane;
            int r  = c >> 3, c8 = c & 7;
            int sc8 = c8 ^ (r & 7);
            gload_lds16(&BT[(size_t)(col0 + r) * K + k0 + sc8 * 8], &Bs[cb * 8]);
        }
        __syncthreads();
#pragma unroll
        for (int kk = 0; kk < 2; ++kk) {
            bf16x8 af[4], bfr[NF];
#pragma unroll
            for (int m = 0; m < 4; ++m) {
                int r   = wm * 64 + m * 16 + l15;
                int blk = (kk * 4 + l4) ^ (r & 7);
                af[m] = *(const bf16x8*)&As[r * 64 + blk * 8];
            }
#pragma unroll
            for (int n = 0; n < NF; ++n) {
                int r   = wn * (BN / 2) + n * 16 + l15;
                int blk = (kk * 4 + l4) ^ (r & 7);
                bfr[n] = *(const bf16x8*)&Bs[r * 64 + blk * 8];
            }
#pragma unroll
            for (int m = 0; m < 4; ++m)
#pragma unroll
                for (int n = 0; n < NF; ++n)
                    acc[m][n] = mfma16(af[m], bfr[n], acc[m][n]);
        }
    }

#pragma unroll
    for (int m = 0; m < 4; ++m) {
        int gr0 = row0 + wm * 64 + m * 16 + l4 * 4;
#pragma unroll
        for (int n = 0; n < NF; ++n) {
            int gc = col0 + wn * (BN / 2) + n * 16 + l15;
            if (MODE == 0) {
                int s = gc >> 10, rem = gc & 1023;
                int hh = rem >> 6, dd = rem & 63;
                int bb = gr0 >> 11, ll = gr0 & 2047;
                if (s == 2) {
                    // V transposed: [bh][d][2048], 4 consecutive l -> 8B store
                    ushort4v o;
#pragma unroll
                    for (int r = 0; r < 4; ++r) o[r] = f2bf(acc[m][n][r]);
                    *(ushort4v*)&V[(((size_t)bb * 16 + hh) * 64 + dd) * 2048 + ll] = o;
                } else {
                    unsigned short* dst = (s == 0) ? Q : Kq;
#pragma unroll
                    for (int r = 0; r < 4; ++r)
                        dst[(((size_t)bb * 16 + hh) * 2048 + ll + r) * 64 + dd] = f2bf(acc[m][n][r]);
                }
            } else {
#pragma unroll
                for (int r = 0; r < 4; ++r)
                    Cf[(size_t)(gr0 + r) * N + gc] = acc[m][n][r];
            }
        }
    }
}

// ---------------- flash attention, swapped-QK 32x32, SINGLE-PASS, gload_lds staging ----------------
// r13/r14-proven kernel, byte-identical to r14.

__global__ __launch_bounds__(256, 4) void attn_kernel(
    const unsigned short* __restrict__ qb,
    const unsigned short* __restrict__ kb,
    const unsigned short* __restrict__ vtb,   // [bh][64][2048] bf16 (V transposed)
    const unsigned char* __restrict__ mask,
    unsigned short* __restrict__ ctxb)        // [b][l][h*64+d] bf16
{
    const int lg = blockIdx.x;
    int u = ((lg & 7) << 6) | (lg >> 3);       // bijective XCD swizzle (512 = 8*64)
    const int qt = u & 15, bh = u >> 4;
    const int b = bh >> 4;
    const int NT = 32;

    const int tid  = threadIdx.x;
    const int lane = tid & 63, wave = tid >> 6;
    const int l31  = lane & 31, hi = lane >> 5;

    __shared__ unsigned short smem[16384];  // K dbuf [0,8K); Vt dbuf [8K,16K) ushorts = 32 KB exactly

    const size_t hoff = (size_t)bh * 131072;
    const unsigned short* qh  = qb  + hoff;
    const unsigned short* kh  = kb  + hoff;
    const unsigned short* vth = vtb + hoff;
    const unsigned char*  mb  = mask + (size_t)b * 2048;

    unsigned long long mball;
    {
        const uint2v* mp = (const uint2v*)mb;
        uint2v a0 = mp[lane * 4 + 0], a1 = mp[lane * 4 + 1];
        uint2v a2 = mp[lane * 4 + 2], a3 = mp[lane * 4 + 3];
        unsigned int any = a0[0] | a0[1] | a1[0] | a1[1] | a2[0] | a2[1] | a3[0] | a3[1];
        mball = __ballot(any != 0u);
    }

    const int qrow = qt * 128 + wave * 32 + l31;
    bf16x8 qf[4];
#pragma unroll
    for (int ki = 0; ki < 4; ++ki)
        qf[ki] = *(const bf16x8*)&qh[(size_t)qrow * 64 + ki * 16 + hi * 8];

    const f32x16 zf = {0,0,0,0,0,0,0,0,0,0,0,0,0,0,0,0};
    bf16x8 ones;
#pragma unroll
    for (int j = 0; j < 8; ++j) ones[j] = (short)0x3F80;

    f32x16 accA = {0,0,0,0,0,0,0,0,0,0,0,0,0,0,0,0};
    f32x16 accB = {0,0,0,0,0,0,0,0,0,0,0,0,0,0,0,0};
    f32x16 accL = {0,0,0,0,0,0,0,0,0,0,0,0,0,0,0,0};  // only [0] is consumed
    float m_r = -1e30f;
    const float SC  = 0.18033688011112042f;            // 0.125 * log2(e)
    const float THR = 44.3614195558365f;               // 8 / SC  (defer-max)

#define STAGE(KB, VB, KV0) do {                                                          \
        _Pragma("unroll")                                                                \
        for (int it_ = 0; it_ < 2; ++it_) {                                              \
            int c_ = it_ * 256 + tid;                                                    \
            int r_ = c_ >> 3, c8_ = c_ & 7;                                              \
            int sc8_ = c8_ ^ (r_ & 7);                                                   \
            gload_lds16(&kh[(size_t)((KV0) + r_) * 64 + sc8_ * 8],                       \
                        &(KB)[(it_ * 256 + wave * 64) * 8]);                             \
            gload_lds16(&vth[(size_t)r_ * 2048 + (KV0) + sc8_ * 8],                      \
                        &(VB)[(it_ * 256 + wave * 64) * 8]);                             \
        }                                                                                \
    } while (0)

    STAGE(smem, smem + 8192, 0);               // prologue -> buffer parity 0

    for (int t = 0; t < NT; ++t) {
        const int kv0 = t * 64;
        unsigned short* Kb = smem + (t & 1) * 4096;
        unsigned short* Vb = smem + 8192 + (t & 1) * 4096;
        __syncthreads();                       // drains vmcnt -> tile t staged; prev readers done
        if (t + 1 < NT) {
            unsigned short* Kn = smem + ((t + 1) & 1) * 4096;
            unsigned short* Vn = smem + 8192 + ((t + 1) & 1) * 4096;
            STAGE(Kn, Vn, kv0 + 64);           // prefetch next tile under compute
        }

        // ---- S^T = K @ Q^T ----
        f32x16 s0, s1;
        __builtin_amdgcn_s_setprio(1);
        {
            int c0 = (hi ^ (l31 & 7)) * 8;
            bf16x8 a0 = *(const bf16x8*)&Kb[l31 * 64 + c0];
            bf16x8 a1 = *(const bf16x8*)&Kb[(32 + l31) * 64 + c0];
            s0 = mfma32(a0, qf[0], zf);
            s1 = mfma32(a1, qf[0], zf);
        }
#pragma unroll
        for (int ki = 1; ki < 4; ++ki) {
            int c0 = ((ki * 2 + hi) ^ (l31 & 7)) * 8;
            bf16x8 a0 = *(const bf16x8*)&Kb[l31 * 64 + c0];
            bf16x8 a1 = *(const bf16x8*)&Kb[(32 + l31) * 64 + c0];
            s0 = mfma32(a0, qf[ki], s0);
            s1 = mfma32(a1, qf[ki], s1);
        }
        __builtin_amdgcn_s_setprio(0);

        if ((mball >> ((t & 31) * 2)) & 3ull) {            // wave-uniform mask slow path
#pragma unroll
            for (int r = 0; r < 16; ++r) {
                int keyl = (r & 3) + 8 * (r >> 2) + 4 * hi;
                if (mb[kv0 + keyl])      s0[r] = -1e30f;
                if (mb[kv0 + 32 + keyl]) s1[r] = -1e30f;
            }
        }

        // ---- online softmax (max3 tree) ----
        float mx;
        {
            float a0 = m3(s0[0],  s0[1],  s0[2]);
            float a1 = m3(s0[3],  s0[4],  s0[5]);
            float a2 = m3(s0[6],  s0[7],  s0[8]);
            float a3 = m3(s0[9],  s0[10], s0[11]);
            float a4 = m3(s0[12], s0[13], s0[14]);
            float b0 = m3(s1[0],  s1[1],  s1[2]);
            float b1 = m3(s1[3],  s1[4],  s1[5]);
            float b2 = m3(s1[6],  s1[7],  s1[8]);
            float b3 = m3(s1[9],  s1[10], s1[11]);
            float b4 = m3(s1[12], s1[13], s1[14]);
            float c0 = m3(a0, a1, s0[15]);
            float c1 = m3(a2, a3, a4);
            float c2 = m3(b0, b1, s1[15]);
            float c3 = m3(b2, b3, b4);
            mx = fmaxf(m3(c0, c1, c2), c3);
        }
        mx = fmaxf(mx, __shfl_xor(mx, 32));
        if (__any(mx > m_r + THR)) {           // defer-max (T13)
            float mn  = fmaxf(m_r, mx);
            float scl = __builtin_amdgcn_exp2f((m_r - mn) * SC);
            m_r = mn;
            accL[0] *= scl;
#pragma unroll
            for (int i = 0; i < 16; ++i) { accA[i] *= scl; accB[i] *= scl; }
        }
        const float nmc = -m_r * SC;
#pragma unroll
        for (int i = 0; i < 16; ++i) {
            s0[i] = __builtin_amdgcn_exp2f(__builtin_fmaf(s0[i], SC, nmc));
            s1[i] = __builtin_amdgcn_exp2f(__builtin_fmaf(s1[i], SC, nmc));
        }

        // ---- P -> bf16 B-fragments (T12) ----
        bf16x8 pf[4];
        {
            union { unsigned int u[4]; bf16x8 v; } f;
            unsigned int w0 = cvtpk_bf16(s0[0],  s0[1]),  w1 = cvtpk_bf16(s0[2],  s0[3]);
            unsigned int w2 = cvtpk_bf16(s0[4],  s0[5]),  w3 = cvtpk_bf16(s0[6],  s0[7]);
            unsigned int w4 = cvtpk_bf16(s0[8],  s0[9]),  w5 = cvtpk_bf16(s0[10], s0[11]);
            unsigned int w6 = cvtpk_bf16(s0[12], s0[13]), w7 = cvtpk_bf16(s0[14], s0[15]);
            plswap(w0, w2); plswap(w1, w3); plswap(w4, w6); plswap(w5, w7);
            f.u[0] = w0; f.u[1] = w1; f.u[2] = w2; f.u[3] = w3; pf[0] = f.v;
            f.u[0] = w4; f.u[1] = w5; f.u[2] = w6; f.u[3] = w7; pf[1] = f.v;
            unsigned int x0 = cvtpk_bf16(s1[0],  s1[1]),  x1 = cvtpk_bf16(s1[2],  s1[3]);
            unsigned int x2 = cvtpk_bf16(s1[4],  s1[5]),  x3 = cvtpk_bf16(s1[6],  s1[7]);
            unsigned int x4 = cvtpk_bf16(s1[8],  s1[9]),  x5 = cvtpk_bf16(s1[10], s1[11]);
            unsigned int x6 = cvtpk_bf16(s1[12], s1[13]), x7 = cvtpk_bf16(s1[14], s1[15]);
            plswap(x0, x2); plswap(x1, x3); plswap(x4, x6); plswap(x5, x7);
            f.u[0] = x0; f.u[1] = x1; f.u[2] = x2; f.u[3] = x3; pf[2] = f.v;
            f.u[0] = x4; f.u[1] = x5; f.u[2] = x6; f.u[3] = x7; pf[3] = f.v;
        }

        // ---- ctx^T += V^T @ P^T ;  l += ones @ P^T ----
        __builtin_amdgcn_s_setprio(1);
#pragma unroll
        for (int ks = 0; ks < 4; ++ks) {
            int c0 = ((ks * 2 + hi) ^ (l31 & 7)) * 8;
            bf16x8 vA = *(const bf16x8*)&Vb[l31 * 64 + c0];
            bf16x8 vB = *(const bf16x8*)&Vb[(32 + l31) * 64 + c0];
            accA = mfma32(vA, pf[ks], accA);
            accB = mfma32(vB, pf[ks], accB);
            accL = mfma32(ones, pf[ks], accL);
        }
        __builtin_amdgcn_s_setprio(0);
    }
#undef STAGE

    // ---- epilogue: normalize, LDS transpose, coalesced bf16 store ----
    __syncthreads();
    const float inv = 1.0f / accL[0];          // accL[0] = sum_k P[k][q=l31]
    const int qloc = wave * 32 + l31;
#pragma unroll
    for (int r = 0; r < 16; ++r) {
        int dA = (r & 3) + 8 * (r >> 2) + 4 * hi;
        smem[qloc * 64 + (dA ^ ((qloc & 7) * 8))]        = f2bf(accA[r] * inv);
        smem[qloc * 64 + ((32 + dA) ^ ((qloc & 7) * 8))] = f2bf(accB[r] * inv);
    }
    __syncthreads();
    const int h = bh & 15;
#pragma unroll
    for (int it = 0; it < 4; ++it) {
        int idx = tid + it * 256;
        int q = idx >> 3, c = idx & 7;
        ushort8 vv = *(const ushort8*)&smem[q * 64 + ((c * 8) ^ ((q & 7) * 8))];
        *(ushort8*)&ctxb[((size_t)(b * 2048 + qt * 128 + q)) * 1024 + h * 64 + c * 8] = vv;
    }
}

// ---------------- launch ----------------

extern "C" void kernel_launch(void* const* d_in, const int* in_sizes, int n_in,
                              void* d_out, int out_size, void* d_ws, size_t ws_size,
                              hipStream_t stream)
{
    const float* x  = (const float*)d_in[0];
    const float* wq = (const float*)d_in[1];
    const float* wk = (const float*)d_in[2];
    const float* wv = (const float*)d_in[3];
    const float* wo = (const float*)d_in[4];
    const unsigned char* mask = (const unsigned char*)d_in[5];
    float* out = (float*)d_out;

    char* ws = (char*)d_ws;
    unsigned short* xb   = (unsigned short*)(ws);                 //  8 MB  [4096][1024]
    unsigned short* wpT  = (unsigned short*)(ws + 8388608);       //  6 MB  [3072][1024]
    unsigned short* woT  = (unsigned short*)(ws + 14680064);      //  2 MB  [1024][1024]
    unsigned short* qb   = (unsigned short*)(ws + 16777216);      //  8 MB  [32][2048][64]
    unsigned short* kb   = (unsigned short*)(ws + 25165824);      //  8 MB  [32][2048][64]
    unsigned short* vtb  = (unsigned short*)(ws + 33554432);      //  8 MB  [32][64][2048] (V^T, written by gemm<0>)
    unsigned short* ctxb = (unsigned short*)(ws + 41943040);      //  8 MB  [4096][1024]

    prep_kernel<<<5120, 256, 0, stream>>>(x, wq, wk, wv, wo, xb, wpT, woT);

    gemm_bt<0,128><<<dim3(24, 32), 256, 0, stream>>>(xb, wpT, nullptr, qb, kb, vtb, 4096, 3072, 1024);

    attn_kernel<<<512, 256, 0, stream>>>(qb, kb, vtb, mask, ctxb);

    gemm_bt<1,64><<<dim3(16, 32), 256, 0, stream>>>(ctxb, woT, out, nullptr, nullptr, nullptr, 4096, 1024, 1024);
}

// Round 18
// 118.071 us; speedup vs baseline: 1.0520x; 1.0042x over previous
//
#include <hip/hip_runtime.h>
#include <stdint.h>

using bf16x8  = __attribute__((ext_vector_type(8))) short;           // 8 bf16 = 4 VGPR
using f32x4   = __attribute__((ext_vector_type(4))) float;
using f32x16  = __attribute__((ext_vector_type(16))) float;
using ushort8 = __attribute__((ext_vector_type(8))) unsigned short;  // 16B
using ushort4v= __attribute__((ext_vector_type(4))) unsigned short;
using uint2v  = __attribute__((ext_vector_type(2))) unsigned int;
using f32x4v  = __attribute__((ext_vector_type(4))) float;

typedef __attribute__((address_space(1))) const unsigned int* gas_ptr;
typedef __attribute__((address_space(3))) unsigned int*       las_ptr;

__device__ __forceinline__ void gload_lds16(const unsigned short* g, unsigned short* l) {
    // async global->LDS, 16B/lane; LDS dest = wave-uniform base + lane*16
    __builtin_amdgcn_global_load_lds((gas_ptr)(const void*)g, (las_ptr)(void*)l, 16, 0, 0);
}

__device__ __forceinline__ unsigned short f2bf(float f) {
    union { float f; uint32_t u; } x; x.f = f;
    uint32_t u = x.u;
    uint32_t r = u + 0x7fffu + ((u >> 16) & 1u);   // RNE
    return (unsigned short)(r >> 16);
}
__device__ __forceinline__ float bf2f(unsigned short u) {
    union { uint32_t u; float f; } x; x.u = ((uint32_t)u) << 16;
    return x.f;
}

__device__ __forceinline__ f32x4 mfma16(bf16x8 a, bf16x8 b, f32x4 c) {
    return __builtin_amdgcn_mfma_f32_16x16x32_bf16(a, b, c, 0, 0, 0);
}
__device__ __forceinline__ f32x16 mfma32(bf16x8 a, bf16x8 b, f32x16 c) {
    return __builtin_amdgcn_mfma_f32_32x32x16_bf16(a, b, c, 0, 0, 0);
}

__device__ __forceinline__ unsigned int cvtpk_bf16(float lo, float hi) {
    unsigned int r;
    asm("v_cvt_pk_bf16_f32 %0, %1, %2" : "=v"(r) : "v"(lo), "v"(hi));
    return r;
}
__device__ __forceinline__ void plswap(unsigned int& a, unsigned int& b) {
    asm("v_permlane32_swap_b32 %0, %1" : "+v"(a), "+v"(b));
}
__device__ __forceinline__ float m3(float a, float b, float c) {   // fuses to v_max3_f32
    return fmaxf(fmaxf(a, b), c);
}

// ---------------- fused prep: cast x + pack w_qkv^T + pack w_o^T ----------------
// blocks [0,4096): cast x->bf16; [4096,4864): wqkv transpose; [4864,5120): wo transpose.

__global__ void prep_kernel(const float* __restrict__ x,
                            const float* __restrict__ wq, const float* __restrict__ wk,
                            const float* __restrict__ wv, const float* __restrict__ wo,
                            unsigned short* __restrict__ xb, unsigned short* __restrict__ wpT,
                            unsigned short* __restrict__ woT)
{
    __shared__ float tile[64][65];
    const int bid = blockIdx.x;
    const int tid = threadIdx.x;

    if (bid < 4096) {
        int i = bid * 256 + tid;
        f32x4v v = ((const f32x4v*)x)[i];
        ushort4v o;
        o[0] = f2bf(v[0]); o[1] = f2bf(v[1]); o[2] = f2bf(v[2]); o[3] = f2bf(v[3]);
        ((ushort4v*)xb)[i] = o;
    } else if (bid < 4864) {
        const int b2 = bid - 4096;
        const int mm = b2 >> 4;                 // 0..47
        const int s = mm >> 4, hh = mm & 15;
        const float* src = ((s == 0) ? wq : (s == 1) ? wk : wv) + (size_t)hh * 1024 * 64;
        const int k0 = (b2 & 15) * 64;
        const int c = tid & 63, rg = tid >> 6;
#pragma unroll
        for (int i = 0; i < 16; ++i) {
            int r = rg * 16 + i;
            tile[r][c] = src[(size_t)(k0 + r) * 64 + c];
        }
        __syncthreads();
        unsigned short* dst = wpT + ((size_t)s * 1024 + hh * 64) * 1024 + k0;
        const int kc = tid & 63, dg = tid >> 6;
#pragma unroll
        for (int i = 0; i < 16; ++i) {
            int d = dg * 16 + i;
            dst[(size_t)d * 1024 + kc] = f2bf(tile[kc][d]);
        }
    } else {
        const int b3 = bid - 4864;
        const int r0 = (b3 >> 4) * 64;          // k
        const int c0 = (b3 & 15) * 64;          // m
        const int c = tid & 63, rg = tid >> 6;
#pragma unroll
        for (int i = 0; i < 16; ++i) {
            int r = rg * 16 + i;
            tile[r][c] = wo[(size_t)(r0 + r) * 1024 + c0 + c];
        }
        __syncthreads();
        const int kc = tid & 63, mg = tid >> 6;
#pragma unroll
        for (int i = 0; i < 16; ++i) {
            int m = mg * 16 + i;
            woT[(size_t)(c0 + m) * 1024 + r0 + kc] = f2bf(tile[kc][m]);
        }
    }
}

// ---------------- GEMM (A row-major [M][K], BT row-major [N][K]) ----------------
// 1-D grid with bijective XCD swizzle (T1): grid % 8 == 0 for both instantiations.
// MODE 0: scatter Q/K into [bh][l][64] and V TRANSPOSED into [bh][64][2048].
// MODE 1: fp32 C row-major.

template<int MODE, int BN>
__global__ __launch_bounds__(256) void gemm_bt(
    const unsigned short* __restrict__ A,
    const unsigned short* __restrict__ BT,
    float* __restrict__ Cf,
    unsigned short* __restrict__ Q,
    unsigned short* __restrict__ Kq,
    unsigned short* __restrict__ V,
    int M, int N, int K)
{
    constexpr int NF = BN / 32;
    __shared__ unsigned short As[128 * 64];
    __shared__ unsigned short Bs[BN * 64];
    const int tid  = threadIdx.x;
    const int lane = tid & 63;
    const int wave = tid >> 6;
    const int wm = wave >> 1, wn = wave & 1;
    const int l15 = lane & 15, l4 = lane >> 4;
    // XCD-aware bijective swizzle: each XCD owns a contiguous chunk of tile space
    // (consecutive tiles share the A row-panel -> L2-resident re-reads).
    const int nwg = gridDim.x;                  // 768 (MODE 0) or 512 (MODE 1); % 8 == 0
    const int cpx = nwg >> 3;
    const int swz = (blockIdx.x & 7) * cpx + (blockIdx.x >> 3);
    const int nxb = N / BN;
    const int row0 = (swz / nxb) * 128;
    const int col0 = (swz % nxb) * BN;

    f32x4 acc[4][NF];
#pragma unroll
    for (int i = 0; i < 4; ++i)
#pragma unroll
        for (int j = 0; j < NF; ++j) acc[i][j] = (f32x4){0.f, 0.f, 0.f, 0.f};

    for (int k0 = 0; k0 < K; k0 += 64) {
        __syncthreads();
#pragma unroll
        for (int it = 0; it < 4; ++it) {
            int cb = (it * 4 + wave) * 64;
            int c  = cb + lane;
            int r  = c >> 3, c8 = c & 7;
            int sc8 = c8 ^ (r & 7);
            gload_lds16(&A[(size_t)(row0 + r) * K + k0 + sc8 * 8], &As[cb * 8]);
        }
#pragma unroll
        for (int it = 0; it < NF; ++it) {
            int cb = (it * 4 + wave) * 64;
            int c  = cb + lane;
            int r  = c >> 3, c8 = c & 7;
            int sc8 = c8 ^ (r & 7);
            gload_lds16(&BT[(size_t)(col0 + r) * K + k0 + sc8 * 8], &Bs[cb * 8]);
        }
        __syncthreads();
#pragma unroll
        for (int kk = 0; kk < 2; ++kk) {
            bf16x8 af[4], bfr[NF];
#pragma unroll
            for (int m = 0; m < 4; ++m) {
                int r   = wm * 64 + m * 16 + l15;
                int blk = (kk * 4 + l4) ^ (r & 7);
                af[m] = *(const bf16x8*)&As[r * 64 + blk * 8];
            }
#pragma unroll
            for (int n = 0; n < NF; ++n) {
                int r   = wn * (BN / 2) + n * 16 + l15;
                int blk = (kk * 4 + l4) ^ (r & 7);
                bfr[n] = *(const bf16x8*)&Bs[r * 64 + blk * 8];
            }
#pragma unroll
            for (int m = 0; m < 4; ++m)
#pragma unroll
                for (int n = 0; n < NF; ++n)
                    acc[m][n] = mfma16(af[m], bfr[n], acc[m][n]);
        }
    }

#pragma unroll
    for (int m = 0; m < 4; ++m) {
        int gr0 = row0 + wm * 64 + m * 16 + l4 * 4;
#pragma unroll
        for (int n = 0; n < NF; ++n) {
            int gc = col0 + wn * (BN / 2) + n * 16 + l15;
            if (MODE == 0) {
                int s = gc >> 10, rem = gc & 1023;
                int hh = rem >> 6, dd = rem & 63;
                int bb = gr0 >> 11, ll = gr0 & 2047;
                if (s == 2) {
                    // V transposed: [bh][d][2048], 4 consecutive l -> 8B store
                    ushort4v o;
#pragma unroll
                    for (int r = 0; r < 4; ++r) o[r] = f2bf(acc[m][n][r]);
                    *(ushort4v*)&V[(((size_t)bb * 16 + hh) * 64 + dd) * 2048 + ll] = o;
                } else {
                    unsigned short* dst = (s == 0) ? Q : Kq;
#pragma unroll
                    for (int r = 0; r < 4; ++r)
                        dst[(((size_t)bb * 16 + hh) * 2048 + ll + r) * 64 + dd] = f2bf(acc[m][n][r]);
                }
            } else {
#pragma unroll
                for (int r = 0; r < 4; ++r)
                    Cf[(size_t)(gr0 + r) * N + gc] = acc[m][n][r];
            }
        }
    }
}

// ---------------- flash attention, swapped-QK 32x32, SINGLE-PASS, gload_lds staging ----------------
// r14/r17-proven kernel, byte-identical.

__global__ __launch_bounds__(256, 4) void attn_kernel(
    const unsigned short* __restrict__ qb,
    const unsigned short* __restrict__ kb,
    const unsigned short* __restrict__ vtb,   // [bh][64][2048] bf16 (V transposed)
    const unsigned char* __restrict__ mask,
    unsigned short* __restrict__ ctxb)        // [b][l][h*64+d] bf16
{
    const int lg = blockIdx.x;
    int u = ((lg & 7) << 6) | (lg >> 3);       // bijective XCD swizzle (512 = 8*64)
    const int qt = u & 15, bh = u >> 4;
    const int b = bh >> 4;
    const int NT = 32;

    const int tid  = threadIdx.x;
    const int lane = tid & 63, wave = tid >> 6;
    const int l31  = lane & 31, hi = lane >> 5;

    __shared__ unsigned short smem[16384];  // K dbuf [0,8K); Vt dbuf [8K,16K) ushorts = 32 KB exactly

    const size_t hoff = (size_t)bh * 131072;
    const unsigned short* qh  = qb  + hoff;
    const unsigned short* kh  = kb  + hoff;
    const unsigned short* vth = vtb + hoff;
    const unsigned char*  mb  = mask + (size_t)b * 2048;

    unsigned long long mball;
    {
        const uint2v* mp = (const uint2v*)mb;
        uint2v a0 = mp[lane * 4 + 0], a1 = mp[lane * 4 + 1];
        uint2v a2 = mp[lane * 4 + 2], a3 = mp[lane * 4 + 3];
        unsigned int any = a0[0] | a0[1] | a1[0] | a1[1] | a2[0] | a2[1] | a3[0] | a3[1];
        mball = __ballot(any != 0u);
    }

    const int qrow = qt * 128 + wave * 32 + l31;
    bf16x8 qf[4];
#pragma unroll
    for (int ki = 0; ki < 4; ++ki)
        qf[ki] = *(const bf16x8*)&qh[(size_t)qrow * 64 + ki * 16 + hi * 8];

    const f32x16 zf = {0,0,0,0,0,0,0,0,0,0,0,0,0,0,0,0};
    bf16x8 ones;
#pragma unroll
    for (int j = 0; j < 8; ++j) ones[j] = (short)0x3F80;

    f32x16 accA = {0,0,0,0,0,0,0,0,0,0,0,0,0,0,0,0};
    f32x16 accB = {0,0,0,0,0,0,0,0,0,0,0,0,0,0,0,0};
    f32x16 accL = {0,0,0,0,0,0,0,0,0,0,0,0,0,0,0,0};  // only [0] is consumed
    float m_r = -1e30f;
    const float SC  = 0.18033688011112042f;            // 0.125 * log2(e)
    const float THR = 44.3614195558365f;               // 8 / SC  (defer-max)

#define STAGE(KB, VB, KV0) do {                                                          \
        _Pragma("unroll")                                                                \
        for (int it_ = 0; it_ < 2; ++it_) {                                              \
            int c_ = it_ * 256 + tid;                                                    \
            int r_ = c_ >> 3, c8_ = c_ & 7;                                              \
            int sc8_ = c8_ ^ (r_ & 7);                                                   \
            gload_lds16(&kh[(size_t)((KV0) + r_) * 64 + sc8_ * 8],                       \
                        &(KB)[(it_ * 256 + wave * 64) * 8]);                             \
            gload_lds16(&vth[(size_t)r_ * 2048 + (KV0) + sc8_ * 8],                      \
                        &(VB)[(it_ * 256 + wave * 64) * 8]);                             \
        }                                                                                \
    } while (0)

    STAGE(smem, smem + 8192, 0);               // prologue -> buffer parity 0

    for (int t = 0; t < NT; ++t) {
        const int kv0 = t * 64;
        unsigned short* Kb = smem + (t & 1) * 4096;
        unsigned short* Vb = smem + 8192 + (t & 1) * 4096;
        __syncthreads();                       // drains vmcnt -> tile t staged; prev readers done
        if (t + 1 < NT) {
            unsigned short* Kn = smem + ((t + 1) & 1) * 4096;
            unsigned short* Vn = smem + 8192 + ((t + 1) & 1) * 4096;
            STAGE(Kn, Vn, kv0 + 64);           // prefetch next tile under compute
        }

        // ---- S^T = K @ Q^T ----
        f32x16 s0, s1;
        __builtin_amdgcn_s_setprio(1);
        {
            int c0 = (hi ^ (l31 & 7)) * 8;
            bf16x8 a0 = *(const bf16x8*)&Kb[l31 * 64 + c0];
            bf16x8 a1 = *(const bf16x8*)&Kb[(32 + l31) * 64 + c0];
            s0 = mfma32(a0, qf[0], zf);
            s1 = mfma32(a1, qf[0], zf);
        }
#pragma unroll
        for (int ki = 1; ki < 4; ++ki) {
            int c0 = ((ki * 2 + hi) ^ (l31 & 7)) * 8;
            bf16x8 a0 = *(const bf16x8*)&Kb[l31 * 64 + c0];
            bf16x8 a1 = *(const bf16x8*)&Kb[(32 + l31) * 64 + c0];
            s0 = mfma32(a0, qf[ki], s0);
            s1 = mfma32(a1, qf[ki], s1);
        }
        __builtin_amdgcn_s_setprio(0);

        if ((mball >> ((t & 31) * 2)) & 3ull) {            // wave-uniform mask slow path
#pragma unroll
            for (int r = 0; r < 16; ++r) {
                int keyl = (r & 3) + 8 * (r >> 2) + 4 * hi;
                if (mb[kv0 + keyl])      s0[r] = -1e30f;
                if (mb[kv0 + 32 + keyl]) s1[r] = -1e30f;
            }
        }

        // ---- online softmax (max3 tree) ----
        float mx;
        {
            float a0 = m3(s0[0],  s0[1],  s0[2]);
            float a1 = m3(s0[3],  s0[4],  s0[5]);
            float a2 = m3(s0[6],  s0[7],  s0[8]);
            float a3 = m3(s0[9],  s0[10], s0[11]);
            float a4 = m3(s0[12], s0[13], s0[14]);
            float b0 = m3(s1[0],  s1[1],  s1[2]);
            float b1 = m3(s1[3],  s1[4],  s1[5]);
            float b2 = m3(s1[6],  s1[7],  s1[8]);
            float b3 = m3(s1[9],  s1[10], s1[11]);
            float b4 = m3(s1[12], s1[13], s1[14]);
            float c0 = m3(a0, a1, s0[15]);
            float c1 = m3(a2, a3, a4);
            float c2 = m3(b0, b1, s1[15]);
            float c3 = m3(b2, b3, b4);
            mx = fmaxf(m3(c0, c1, c2), c3);
        }
        mx = fmaxf(mx, __shfl_xor(mx, 32));
        if (__any(mx > m_r + THR)) {           // defer-max (T13)
            float mn  = fmaxf(m_r, mx);
            float scl = __builtin_amdgcn_exp2f((m_r - mn) * SC);
            m_r = mn;
            accL[0] *= scl;
#pragma unroll
            for (int i = 0; i < 16; ++i) { accA[i] *= scl; accB[i] *= scl; }
        }
        const float nmc = -m_r * SC;
#pragma unroll
        for (int i = 0; i < 16; ++i) {
            s0[i] = __builtin_amdgcn_exp2f(__builtin_fmaf(s0[i], SC, nmc));
            s1[i] = __builtin_amdgcn_exp2f(__builtin_fmaf(s1[i], SC, nmc));
        }

        // ---- P -> bf16 B-fragments (T12) ----
        bf16x8 pf[4];
        {
            union { unsigned int u[4]; bf16x8 v; } f;
            unsigned int w0 = cvtpk_bf16(s0[0],  s0[1]),  w1 = cvtpk_bf16(s0[2],  s0[3]);
            unsigned int w2 = cvtpk_bf16(s0[4],  s0[5]),  w3 = cvtpk_bf16(s0[6],  s0[7]);
            unsigned int w4 = cvtpk_bf16(s0[8],  s0[9]),  w5 = cvtpk_bf16(s0[10], s0[11]);
            unsigned int w6 = cvtpk_bf16(s0[12], s0[13]), w7 = cvtpk_bf16(s0[14], s0[15]);
            plswap(w0, w2); plswap(w1, w3); plswap(w4, w6); plswap(w5, w7);
            f.u[0] = w0; f.u[1] = w1; f.u[2] = w2; f.u[3] = w3; pf[0] = f.v;
            f.u[0] = w4; f.u[1] = w5; f.u[2] = w6; f.u[3] = w7; pf[1] = f.v;
            unsigned int x0 = cvtpk_bf16(s1[0],  s1[1]),  x1 = cvtpk_bf16(s1[2],  s1[3]);
            unsigned int x2 = cvtpk_bf16(s1[4],  s1[5]),  x3 = cvtpk_bf16(s1[6],  s1[7]);
            unsigned int x4 = cvtpk_bf16(s1[8],  s1[9]),  x5 = cvtpk_bf16(s1[10], s1[11]);
            unsigned int x6 = cvtpk_bf16(s1[12], s1[13]), x7 = cvtpk_bf16(s1[14], s1[15]);
            plswap(x0, x2); plswap(x1, x3); plswap(x4, x6); plswap(x5, x7);
            f.u[0] = x0; f.u[1] = x1; f.u[2] = x2; f.u[3] = x3; pf[2] = f.v;
            f.u[0] = x4; f.u[1] = x5; f.u[2] = x6; f.u[3] = x7; pf[3] = f.v;
        }

        // ---- ctx^T += V^T @ P^T ;  l += ones @ P^T ----
        __builtin_amdgcn_s_setprio(1);
#pragma unroll
        for (int ks = 0; ks < 4; ++ks) {
            int c0 = ((ks * 2 + hi) ^ (l31 & 7)) * 8;
            bf16x8 vA = *(const bf16x8*)&Vb[l31 * 64 + c0];
            bf16x8 vB = *(const bf16x8*)&Vb[(32 + l31) * 64 + c0];
            accA = mfma32(vA, pf[ks], accA);
            accB = mfma32(vB, pf[ks], accB);
            accL = mfma32(ones, pf[ks], accL);
        }
        __builtin_amdgcn_s_setprio(0);
    }
#undef STAGE

    // ---- epilogue: normalize, LDS transpose, coalesced bf16 store ----
    __syncthreads();
    const float inv = 1.0f / accL[0];          // accL[0] = sum_k P[k][q=l31]
    const int qloc = wave * 32 + l31;
#pragma unroll
    for (int r = 0; r < 16; ++r) {
        int dA = (r & 3) + 8 * (r >> 2) + 4 * hi;
        smem[qloc * 64 + (dA ^ ((qloc & 7) * 8))]        = f2bf(accA[r] * inv);
        smem[qloc * 64 + ((32 + dA) ^ ((qloc & 7) * 8))] = f2bf(accB[r] * inv);
    }
    __syncthreads();
    const int h = bh & 15;
#pragma unroll
    for (int it = 0; it < 4; ++it) {
        int idx = tid + it * 256;
        int q = idx >> 3, c = idx & 7;
        ushort8 vv = *(const ushort8*)&smem[q * 64 + ((c * 8) ^ ((q & 7) * 8))];
        *(ushort8*)&ctxb[((size_t)(b * 2048 + qt * 128 + q)) * 1024 + h * 64 + c * 8] = vv;
    }
}

// ---------------- launch ----------------

extern "C" void kernel_launch(void* const* d_in, const int* in_sizes, int n_in,
                              void* d_out, int out_size, void* d_ws, size_t ws_size,
                              hipStream_t stream)
{
    const float* x  = (const float*)d_in[0];
    const float* wq = (const float*)d_in[1];
    const float* wk = (const float*)d_in[2];
    const float* wv = (const float*)d_in[3];
    const float* wo = (const float*)d_in[4];
    const unsigned char* mask = (const unsigned char*)d_in[5];
    float* out = (float*)d_out;

    char* ws = (char*)d_ws;
    unsigned short* xb   = (unsigned short*)(ws);                 //  8 MB  [4096][1024]
    unsigned short* wpT  = (unsigned short*)(ws + 8388608);       //  6 MB  [3072][1024]
    unsigned short* woT  = (unsigned short*)(ws + 14680064);      //  2 MB  [1024][1024]
    unsigned short* qb   = (unsigned short*)(ws + 16777216);      //  8 MB  [32][2048][64]
    unsigned short* kb   = (unsigned short*)(ws + 25165824);      //  8 MB  [32][2048][64]
    unsigned short* vtb  = (unsigned short*)(ws + 33554432);      //  8 MB  [32][64][2048] (V^T, written by gemm<0>)
    unsigned short* ctxb = (unsigned short*)(ws + 41943040);      //  8 MB  [4096][1024]

    prep_kernel<<<5120, 256, 0, stream>>>(x, wq, wk, wv, wo, xb, wpT, woT);

    gemm_bt<0,128><<<768, 256, 0, stream>>>(xb, wpT, nullptr, qb, kb, vtb, 4096, 3072, 1024);

    attn_kernel<<<512, 256, 0, stream>>>(qb, kb, vtb, mask, ctxb);

    gemm_bt<1,64><<<512, 256, 0, stream>>>(ctxb, woT, out, nullptr, nullptr, nullptr, 4096, 1024, 1024);
}